// Round 3
// baseline (1223.923 us; speedup 1.0000x reference)
//
#include <hip/hip_runtime.h>
#include <stdint.h>

#define NB 8
#define NPTS 100000
#define NS 4096
#define NN 32
#define NCH 64
#define TLG 17
#define TSLOTS (1 << TLG)          // 131072 hash slots per batch
#define TMASK (TSLOTS - 1)

// d_out float layout (element offsets)
#define OUT_MAIN 0ull                          // [8,4096,32,67]
#define OUT_SRC  70254592ull                   // [8,4096,32]
#define OUT_CTR  71303168ull                   // [8,4096]
#define OUT_CF   71335936ull                   // [8,100000]
#define OUT_SF   72135936ull                   // [8,100000]

__host__ __device__ static inline uint32_t rotl32(uint32_t v, int d) {
    return (v << d) | (v >> (32 - d));
}

// JAX threefry2x32 (5 groups of 4 rounds), exact.
__host__ __device__ static inline void tf2x32(uint32_t k0, uint32_t k1,
                                              uint32_t x0, uint32_t x1,
                                              uint32_t& o0, uint32_t& o1) {
    uint32_t ks2 = k0 ^ k1 ^ 0x1BD11BDAu;
    x0 += k0; x1 += k1;
    x0 += x1; x1 = rotl32(x1, 13); x1 ^= x0;
    x0 += x1; x1 = rotl32(x1, 15); x1 ^= x0;
    x0 += x1; x1 = rotl32(x1, 26); x1 ^= x0;
    x0 += x1; x1 = rotl32(x1, 6);  x1 ^= x0;
    x0 += k1; x1 += ks2 + 1u;
    x0 += x1; x1 = rotl32(x1, 17); x1 ^= x0;
    x0 += x1; x1 = rotl32(x1, 29); x1 ^= x0;
    x0 += x1; x1 = rotl32(x1, 16); x1 ^= x0;
    x0 += x1; x1 = rotl32(x1, 24); x1 ^= x0;
    x0 += ks2; x1 += k0 + 2u;
    x0 += x1; x1 = rotl32(x1, 13); x1 ^= x0;
    x0 += x1; x1 = rotl32(x1, 15); x1 ^= x0;
    x0 += x1; x1 = rotl32(x1, 26); x1 ^= x0;
    x0 += x1; x1 = rotl32(x1, 6);  x1 ^= x0;
    x0 += k0; x1 += k1 + 3u;
    x0 += x1; x1 = rotl32(x1, 17); x1 ^= x0;
    x0 += x1; x1 = rotl32(x1, 29); x1 ^= x0;
    x0 += x1; x1 = rotl32(x1, 16); x1 ^= x0;
    x0 += x1; x1 = rotl32(x1, 24); x1 ^= x0;
    x0 += k1; x1 += ks2 + 4u;
    x0 += x1; x1 = rotl32(x1, 13); x1 ^= x0;
    x0 += x1; x1 = rotl32(x1, 15); x1 ^= x0;
    x0 += x1; x1 = rotl32(x1, 26); x1 ^= x0;
    x0 += x1; x1 = rotl32(x1, 6);  x1 ^= x0;
    x0 += ks2; x1 += k0 + 5u;
    o0 = x0; o1 = x1;
}

struct RngKeys {
    uint32_t c0[NB], c1[NB];   // partitionable k2 keys: centers
    uint32_t n0[NB], n1[NB];   // partitionable k2 keys: neighbor draws
};

// partitionable random_bits(key, 32, ...): element u -> o0^o1, counter (0,u)
__device__ static inline uint32_t pbits32(uint32_t k0, uint32_t k1, uint32_t u) {
    uint32_t o0, o1;
    tf2x32(k0, k1, 0u, u, o0, o1);
    return o0 ^ o1;
}

// packed voxel key == reference hash: (vx+512)<<20 | (vy+512)<<10 | (vz+512)
__device__ static inline int voxhash(const float* __restrict__ p) {
    int vx = (int)floorf(p[0] * 4.0f);
    int vy = (int)floorf(p[1] * 4.0f);
    int vz = (int)floorf(p[2] * 4.0f);
    return ((vx + 512) << 20) | ((vy + 512) << 10) | (vz + 512);
}

__device__ static inline int hslot(int hk) {
    return (int)(((uint32_t)hk * 2654435761u) >> (32 - TLG)) & TMASK;
}

// find slot of existing key (guaranteed present)
__device__ static inline int probe_find(const int* __restrict__ key, int base, int hk) {
    int slot = hslot(hk);
    while (key[base + slot] != hk) slot = (slot + 1) & TMASK;
    return slot;
}

// ---------------- P1: insert + count -----------------
__global__ void k_insert(const float* __restrict__ pos,
                         int* __restrict__ tab_key, int* __restrict__ tab_cnt) {
    int t = blockIdx.x * blockDim.x + threadIdx.x;   // exact: NB*NPTS
    int b = t / NPTS;
    int hk = voxhash(pos + (size_t)t * 3);
    int base = b << TLG;
    int slot = hslot(hk);
    while (true) {
        int prev = atomicCAS(&tab_key[base + slot], -1, hk);
        if (prev == -1 || prev == hk) break;
        slot = (slot + 1) & TMASK;
    }
    atomicAdd(&tab_cnt[base + slot], 1);
}

// ---------------- P2: assign bucket starts, zero fill counters ------------
__global__ void k_starts(int* __restrict__ tab_cnt, int* __restrict__ tab_start,
                         int* __restrict__ bctr) {
    int t = blockIdx.x * blockDim.x + threadIdx.x;   // exact: NB*TSLOTS
    int b = t >> TLG;
    int c = tab_cnt[t];
    if (c > 0) {
        tab_start[t] = atomicAdd(&bctr[b], c);
        tab_cnt[t] = 0;                              // becomes fill counter
    }
}

// ---------------- P3: scatter arrival order -----------------
__global__ void k_scatter(const float* __restrict__ pos,
                          const int* __restrict__ tab_key, int* __restrict__ tab_cnt,
                          const int* __restrict__ tab_start, int* __restrict__ listA) {
    int t = blockIdx.x * blockDim.x + threadIdx.x;   // exact: NB*NPTS
    int b = t / NPTS, i = t - b * NPTS;
    int hk = voxhash(pos + (size_t)t * 3);
    int base = b << TLG;
    int slot = probe_find(tab_key, base, hk);
    int a = atomicAdd(&tab_cnt[base + slot], 1);     // restores cnt as side effect
    listA[(size_t)b * NPTS + tab_start[base + slot] + a] = i;
}

// ---------------- P4: rank within bucket -> index-sorted lists ------------
__global__ void k_rank(const float* __restrict__ pos,
                       const int* __restrict__ tab_key, const int* __restrict__ tab_cnt,
                       const int* __restrict__ tab_start,
                       const int* __restrict__ listA, int* __restrict__ listB) {
    int t = blockIdx.x * blockDim.x + threadIdx.x;   // exact: NB*NPTS
    int b = t / NPTS, i = t - b * NPTS;
    int hk = voxhash(pos + (size_t)t * 3);
    int base = b << TLG;
    int slot = probe_find(tab_key, base, hk);
    int s0 = tab_start[base + slot];
    int c = tab_cnt[base + slot];
    const int* L = listA + (size_t)b * NPTS + s0;
    int rank = 0;
    for (int k = 0; k < c; k++) rank += (L[k] < i) ? 1 : 0;
    listB[(size_t)b * NPTS + s0 + rank] = i;
}

// ---------------- centers (+ packed center voxel key) -----------------
__global__ void k_centers(RngKeys keys, const float* __restrict__ pos,
                          int* __restrict__ centers_ws, int* __restrict__ ctrhk_ws,
                          float* __restrict__ out_ctr, float* __restrict__ out_cf) {
    int t = blockIdx.x * blockDim.x + threadIdx.x;   // exact: NB*NS
    int b = t / NS, s = t - b * NS;
    uint32_t lower = pbits32(keys.c0[b], keys.c1[b], (uint32_t)s);
    int c = (int)(lower % 100000u);                  // randint multiplier==0 path
    centers_ws[t] = c;
    ctrhk_ws[t] = voxhash(pos + ((size_t)b * NPTS + c) * 3);
    out_ctr[t] = (float)c;
    out_cf[(size_t)b * NPTS + c] = 1.0f;
}

// ---------------- per-(b,s,bin) bucket lookup -----------------
__global__ void k_bins(const int* __restrict__ tab_key, const int* __restrict__ tab_cnt,
                       const int* __restrict__ tab_start, const int* __restrict__ ctrhk_ws,
                       int* __restrict__ lo_ws, int* __restrict__ cnt_ws) {
    int t = blockIdx.x * blockDim.x + threadIdx.x;   // exact: NB*NS*27
    int bin = t % 27;
    int bs = t / 27;
    int b = bs / NS;
    // neighbor voxel key by pure integer offset (coords never at the ±512 edge)
    int hk = ctrhk_ws[bs] + ((bin / 9) - 1) * (1 << 20)
                          + (((bin / 3) % 3) - 1) * (1 << 10)
                          + ((bin % 3) - 1);
    int base = b << TLG;
    int slot = hslot(hk);
    int lo = 0, c = 0;
    while (true) {
        int k = tab_key[base + slot];
        if (k == hk) { lo = tab_start[base + slot]; c = tab_cnt[base + slot]; break; }
        if (k == -1) break;
        slot = (slot + 1) & TMASK;
    }
    lo_ws[t] = lo;
    cnt_ws[t] = c;
}

// ---------------- cumsum over 27 bins (in place) -----------------
__global__ void k_cum(int* __restrict__ cnt_cum) {
    int t = blockIdx.x * blockDim.x + threadIdx.x;   // exact: NB*NS
    int acc = 0;
    int* a = cnt_cum + (size_t)t * 27;
    for (int i = 0; i < 27; i++) { acc += a[i]; a[i] = acc; }
}

// ---------------- neighbor selection -----------------
__global__ void k_select(RngKeys keys, const int* __restrict__ listB,
                         const int* __restrict__ lo_ws, const int* __restrict__ cum_ws,
                         int* __restrict__ src_ws,
                         float* __restrict__ out_src, float* __restrict__ out_sf) {
    int t = blockIdx.x * blockDim.x + threadIdx.x;   // exact: NB*NS*NN
    int b = t >> 17;                                  // NS*NN = 131072
    int u = t & (NS * NN - 1);
    uint32_t lower = pbits32(keys.n0[b], keys.n1[b], (uint32_t)u);
    int bs = b * NS + (u >> 5);
    const int* cum = cum_ws + (size_t)bs * 27;
    int total = cum[26];
    int r = (int)(lower & 0x3FFFFFFFu) % total;       // span=2^30 -> multiplier==0 path
    int slot = 0, prev = 0;
    #pragma unroll
    for (int i = 0; i < 27; i++) {
        int ci = cum[i];
        if (r >= ci) { slot = i + 1; prev = ci; }
    }
    int pos_in = lo_ws[(size_t)bs * 27 + slot] + (r - prev);
    int src = listB[(size_t)b * NPTS + pos_in];
    src_ws[t] = src;
    out_src[t] = (float)src;
    out_sf[(size_t)b * NPTS + src] = 1.0f;
}

// ---------------- output gather: 16 lanes/row, LDS-staged float4 writes ----
__global__ void k_gather(const float* __restrict__ pos, const float* __restrict__ feat,
                         const int* __restrict__ centers_ws, const int* __restrict__ src_ws,
                         float* __restrict__ out) {
    __shared__ float sbuf[16 * 67];                   // 4288 B
    int t = threadIdx.x;
    int g = t >> 4, q = t & 15;
    long long row0 = (long long)blockIdx.x * 16;      // exact: NB*NS*NN rows
    long long row = row0 + g;
    int b = (int)(row >> 17);
    int u = (int)(row & (NS * NN - 1));
    int s = u >> 5;
    int src = src_ws[row];
    const float4 fv = *(const float4*)(feat + ((size_t)b * NPTS + src) * NCH + 4 * q);
    float* sb = sbuf + g * 67;
    sb[3 + 4 * q + 0] = fv.x;
    sb[3 + 4 * q + 1] = fv.y;
    sb[3 + 4 * q + 2] = fv.z;
    sb[3 + 4 * q + 3] = fv.w;
    if (q < 3) {
        int ctr = centers_ws[b * NS + s];
        sb[q] = pos[((size_t)b * NPTS + src) * 3 + q]
              - pos[((size_t)b * NPTS + ctr) * 3 + q];
    }
    __syncthreads();
    float4* ob = (float4*)(out + (size_t)row0 * 67);  // 4288 B, 16B-aligned
    const float4* sv = (const float4*)sbuf;
    ob[t] = sv[t];
    if (t < 12) ob[256 + t] = sv[256 + t];
}

extern "C" void kernel_launch(void* const* d_in, const int* in_sizes, int n_in,
                              void* d_out, int out_size, void* d_ws, size_t ws_size,
                              hipStream_t stream) {
    (void)in_sizes; (void)n_in; (void)out_size; (void)ws_size;
    const float* pos = (const float*)d_in[0];
    const float* feat = (const float*)d_in[1];
    float* out = (float*)d_out;

    // ---- host-side JAX key-chain (threefry partitionable mode) ----
    RngKeys keys;
    for (int b = 0; b < NB; b++) {
        uint32_t rk0, rk1, kc0, kc1, kn0, kn1;
        tf2x32(0u, 42u, 0u, (uint32_t)b, rk0, rk1);
        tf2x32(rk0, rk1, 0u, 0u, kc0, kc1);
        tf2x32(rk0, rk1, 0u, 1u, kn0, kn1);
        tf2x32(kc0, kc1, 0u, 1u, keys.c0[b], keys.c1[b]);
        tf2x32(kn0, kn1, 0u, 1u, keys.n0[b], keys.n1[b]);
    }

    // ---- workspace layout (~26.2 MB) ----
    int* tab_key    = (int*)d_ws;                    // NB*TSLOTS
    int* tab_cnt    = tab_key + (size_t)NB * TSLOTS; // NB*TSLOTS
    int* bctr       = tab_cnt + (size_t)NB * TSLOTS; // NB  (contiguous w/ tab_cnt)
    int* tab_start  = bctr + NB;                     // NB*TSLOTS
    int* listA      = tab_start + (size_t)NB * TSLOTS; // NB*NPTS
    int* listB      = listA + (size_t)NB * NPTS;     // NB*NPTS
    int* lo_ws      = listB + (size_t)NB * NPTS;     // NB*NS*27
    int* cum_ws     = lo_ws + (size_t)NB * NS * 27;  // NB*NS*27
    int* centers_ws = cum_ws + (size_t)NB * NS * 27; // NB*NS
    int* ctrhk_ws   = centers_ws + (size_t)NB * NS;  // NB*NS
    int* src_ws     = ctrhk_ws + (size_t)NB * NS;    // NB*NS*NN

    // init: keys -> -1; counts + batch counters -> 0; flag outputs -> 0
    hipMemsetAsync(tab_key, 0xFF, (size_t)NB * TSLOTS * 4, stream);
    hipMemsetAsync(tab_cnt, 0, ((size_t)NB * TSLOTS + NB) * 4, stream);
    hipMemsetAsync((char*)d_out + OUT_CF * 4, 0, (size_t)(2 * NB * NPTS) * 4, stream);

    k_insert <<<(NB * NPTS) / 256, 256, 0, stream>>>(pos, tab_key, tab_cnt);
    k_starts <<<(NB * TSLOTS) / 256, 256, 0, stream>>>(tab_cnt, tab_start, bctr);
    k_scatter<<<(NB * NPTS) / 256, 256, 0, stream>>>(pos, tab_key, tab_cnt, tab_start, listA);
    k_rank   <<<(NB * NPTS) / 256, 256, 0, stream>>>(pos, tab_key, tab_cnt, tab_start,
                                                     listA, listB);
    k_centers<<<(NB * NS) / 256, 256, 0, stream>>>(keys, pos, centers_ws, ctrhk_ws,
                                                   out + OUT_CTR, out + OUT_CF);
    k_bins   <<<(NB * NS * 27) / 256, 256, 0, stream>>>(tab_key, tab_cnt, tab_start,
                                                        ctrhk_ws, lo_ws, cum_ws);
    k_cum    <<<(NB * NS) / 256, 256, 0, stream>>>(cum_ws);
    k_select <<<(NB * NS * NN) / 256, 256, 0, stream>>>(keys, listB, lo_ws, cum_ws,
                                                        src_ws, out + OUT_SRC, out + OUT_SF);
    k_gather <<<(NB * NS * NN) / 16, 256, 0, stream>>>(pos, feat, centers_ws, src_ws, out);
}

// Round 4
// 435.990 us; speedup vs baseline: 2.8072x; 2.8072x over previous
//
#include <hip/hip_runtime.h>
#include <stdint.h>

#define NB 8
#define NPTS 100000
#define NS 4096
#define NN 32
#define NCH 64
#define TLG 17
#define TSLOTS (1 << TLG)          // 131072 hash slots per batch
#define TMASK (TSLOTS - 1)

// d_out float layout (element offsets)
#define OUT_MAIN 0ull                          // [8,4096,32,67]
#define OUT_SRC  70254592ull                   // [8,4096,32]
#define OUT_CTR  71303168ull                   // [8,4096]
#define OUT_CF   71335936ull                   // [8,100000]
#define OUT_SF   72135936ull                   // [8,100000]

__host__ __device__ static inline uint32_t rotl32(uint32_t v, int d) {
    return (v << d) | (v >> (32 - d));
}

// JAX threefry2x32 (5 groups of 4 rounds), exact.
__host__ __device__ static inline void tf2x32(uint32_t k0, uint32_t k1,
                                              uint32_t x0, uint32_t x1,
                                              uint32_t& o0, uint32_t& o1) {
    uint32_t ks2 = k0 ^ k1 ^ 0x1BD11BDAu;
    x0 += k0; x1 += k1;
    x0 += x1; x1 = rotl32(x1, 13); x1 ^= x0;
    x0 += x1; x1 = rotl32(x1, 15); x1 ^= x0;
    x0 += x1; x1 = rotl32(x1, 26); x1 ^= x0;
    x0 += x1; x1 = rotl32(x1, 6);  x1 ^= x0;
    x0 += k1; x1 += ks2 + 1u;
    x0 += x1; x1 = rotl32(x1, 17); x1 ^= x0;
    x0 += x1; x1 = rotl32(x1, 29); x1 ^= x0;
    x0 += x1; x1 = rotl32(x1, 16); x1 ^= x0;
    x0 += x1; x1 = rotl32(x1, 24); x1 ^= x0;
    x0 += ks2; x1 += k0 + 2u;
    x0 += x1; x1 = rotl32(x1, 13); x1 ^= x0;
    x0 += x1; x1 = rotl32(x1, 15); x1 ^= x0;
    x0 += x1; x1 = rotl32(x1, 26); x1 ^= x0;
    x0 += x1; x1 = rotl32(x1, 6);  x1 ^= x0;
    x0 += k0; x1 += k1 + 3u;
    x0 += x1; x1 = rotl32(x1, 17); x1 ^= x0;
    x0 += x1; x1 = rotl32(x1, 29); x1 ^= x0;
    x0 += x1; x1 = rotl32(x1, 16); x1 ^= x0;
    x0 += x1; x1 = rotl32(x1, 24); x1 ^= x0;
    x0 += k1; x1 += ks2 + 4u;
    x0 += x1; x1 = rotl32(x1, 13); x1 ^= x0;
    x0 += x1; x1 = rotl32(x1, 15); x1 ^= x0;
    x0 += x1; x1 = rotl32(x1, 26); x1 ^= x0;
    x0 += x1; x1 = rotl32(x1, 6);  x1 ^= x0;
    x0 += ks2; x1 += k0 + 5u;
    o0 = x0; o1 = x1;
}

struct RngKeys {
    uint32_t c0[NB], c1[NB];   // partitionable k2 keys: centers
    uint32_t n0[NB], n1[NB];   // partitionable k2 keys: neighbor draws
};

// partitionable random_bits(key, 32, ...): element u -> o0^o1, counter (0,u)
__device__ static inline uint32_t pbits32(uint32_t k0, uint32_t k1, uint32_t u) {
    uint32_t o0, o1;
    tf2x32(k0, k1, 0u, u, o0, o1);
    return o0 ^ o1;
}

// packed voxel key == reference hash: (vx+512)<<20 | (vy+512)<<10 | (vz+512)
__device__ static inline int voxhash(const float* __restrict__ p) {
    int vx = (int)floorf(p[0] * 4.0f);
    int vy = (int)floorf(p[1] * 4.0f);
    int vz = (int)floorf(p[2] * 4.0f);
    return ((vx + 512) << 20) | ((vy + 512) << 10) | (vz + 512);
}

__device__ static inline int hslot(int hk) {
    return (int)(((uint32_t)hk * 2654435761u) >> (32 - TLG)) & TMASK;
}

// find slot of existing key (guaranteed present)
__device__ static inline int probe_find(const int* __restrict__ key, int base, int hk) {
    int slot = hslot(hk);
    while (key[base + slot] != hk) slot = (slot + 1) & TMASK;
    return slot;
}

// ---------------- P1: insert + count -----------------
__global__ void k_insert(const float* __restrict__ pos,
                         int* __restrict__ tab_key, int* __restrict__ tab_cnt) {
    int t = blockIdx.x * blockDim.x + threadIdx.x;   // exact: NB*NPTS
    int b = t / NPTS;
    int hk = voxhash(pos + (size_t)t * 3);
    int base = b << TLG;
    int slot = hslot(hk);
    while (true) {
        int prev = atomicCAS(&tab_key[base + slot], -1, hk);
        if (prev == -1 || prev == hk) break;
        slot = (slot + 1) & TMASK;
    }
    atomicAdd(&tab_cnt[base + slot], 1);
}

// ---------------- P2: assign bucket starts (block scan, 1 atomic/block) ----
__global__ void k_starts(int* __restrict__ tab_cnt, int* __restrict__ tab_start,
                         int* __restrict__ bctr) {
    __shared__ int sdata[256];
    __shared__ int sbase;
    int t = blockIdx.x * blockDim.x + threadIdx.x;   // exact: NB*TSLOTS
    int tid = threadIdx.x;
    int b = t >> TLG;                                // uniform per block
    int c = tab_cnt[t];
    sdata[tid] = c;
    __syncthreads();
    // Hillis-Steele inclusive scan over 256 elements
    for (int off = 1; off < 256; off <<= 1) {
        int x = (tid >= off) ? sdata[tid - off] : 0;
        __syncthreads();
        sdata[tid] += x;
        __syncthreads();
    }
    if (tid == 255) sbase = atomicAdd(&bctr[b], sdata[255]);
    __syncthreads();
    if (c > 0) {
        tab_start[t] = sbase + sdata[tid] - c;       // exclusive prefix
        tab_cnt[t] = 0;                              // becomes fill counter
    }
}

// ---------------- P3: scatter arrival order -----------------
__global__ void k_scatter(const float* __restrict__ pos,
                          const int* __restrict__ tab_key, int* __restrict__ tab_cnt,
                          const int* __restrict__ tab_start, int* __restrict__ listA) {
    int t = blockIdx.x * blockDim.x + threadIdx.x;   // exact: NB*NPTS
    int b = t / NPTS, i = t - b * NPTS;
    int hk = voxhash(pos + (size_t)t * 3);
    int base = b << TLG;
    int slot = probe_find(tab_key, base, hk);
    int a = atomicAdd(&tab_cnt[base + slot], 1);     // restores cnt as side effect
    listA[(size_t)b * NPTS + tab_start[base + slot] + a] = i;
}

// ---------------- P4: rank within bucket -> index-sorted lists ------------
__global__ void k_rank(const float* __restrict__ pos,
                       const int* __restrict__ tab_key, const int* __restrict__ tab_cnt,
                       const int* __restrict__ tab_start,
                       const int* __restrict__ listA, int* __restrict__ listB) {
    int t = blockIdx.x * blockDim.x + threadIdx.x;   // exact: NB*NPTS
    int b = t / NPTS, i = t - b * NPTS;
    int hk = voxhash(pos + (size_t)t * 3);
    int base = b << TLG;
    int slot = probe_find(tab_key, base, hk);
    int s0 = tab_start[base + slot];
    int c = tab_cnt[base + slot];
    const int* L = listA + (size_t)b * NPTS + s0;
    int rank = 0;
    for (int k = 0; k < c; k++) rank += (L[k] < i) ? 1 : 0;
    listB[(size_t)b * NPTS + s0 + rank] = i;
}

// ---------------- centers (+ packed center voxel key) -----------------
__global__ void k_centers(RngKeys keys, const float* __restrict__ pos,
                          int* __restrict__ centers_ws, int* __restrict__ ctrhk_ws,
                          float* __restrict__ out_ctr, float* __restrict__ out_cf) {
    int t = blockIdx.x * blockDim.x + threadIdx.x;   // exact: NB*NS
    int b = t / NS, s = t - b * NS;
    uint32_t lower = pbits32(keys.c0[b], keys.c1[b], (uint32_t)s);
    int c = (int)(lower % 100000u);                  // randint multiplier==0 path
    centers_ws[t] = c;
    ctrhk_ws[t] = voxhash(pos + ((size_t)b * NPTS + c) * 3);
    out_ctr[t] = (float)c;
    out_cf[(size_t)b * NPTS + c] = 1.0f;
}

// ---------------- per-(b,s,bin) bucket lookup -----------------
__global__ void k_bins(const int* __restrict__ tab_key, const int* __restrict__ tab_cnt,
                       const int* __restrict__ tab_start, const int* __restrict__ ctrhk_ws,
                       int* __restrict__ lo_ws, int* __restrict__ cnt_ws) {
    int t = blockIdx.x * blockDim.x + threadIdx.x;   // exact: NB*NS*27
    int bin = t % 27;
    int bs = t / 27;
    int b = bs / NS;
    // neighbor voxel key by pure integer offset (coords never at the ±512 edge)
    int hk = ctrhk_ws[bs] + ((bin / 9) - 1) * (1 << 20)
                          + (((bin / 3) % 3) - 1) * (1 << 10)
                          + ((bin % 3) - 1);
    int base = b << TLG;
    int slot = hslot(hk);
    int lo = 0, c = 0;
    while (true) {
        int k = tab_key[base + slot];
        if (k == hk) { lo = tab_start[base + slot]; c = tab_cnt[base + slot]; break; }
        if (k == -1) break;
        slot = (slot + 1) & TMASK;
    }
    lo_ws[t] = lo;
    cnt_ws[t] = c;
}

// ---------------- cumsum over 27 bins (in place) -----------------
__global__ void k_cum(int* __restrict__ cnt_cum) {
    int t = blockIdx.x * blockDim.x + threadIdx.x;   // exact: NB*NS
    int acc = 0;
    int* a = cnt_cum + (size_t)t * 27;
    for (int i = 0; i < 27; i++) { acc += a[i]; a[i] = acc; }
}

// ---------------- neighbor selection -----------------
__global__ void k_select(RngKeys keys, const int* __restrict__ listB,
                         const int* __restrict__ lo_ws, const int* __restrict__ cum_ws,
                         int* __restrict__ src_ws,
                         float* __restrict__ out_src, float* __restrict__ out_sf) {
    int t = blockIdx.x * blockDim.x + threadIdx.x;   // exact: NB*NS*NN
    int b = t >> 17;                                  // NS*NN = 131072
    int u = t & (NS * NN - 1);
    uint32_t lower = pbits32(keys.n0[b], keys.n1[b], (uint32_t)u);
    int bs = b * NS + (u >> 5);
    const int* cum = cum_ws + (size_t)bs * 27;
    int total = cum[26];
    int r = (int)(lower & 0x3FFFFFFFu) % total;       // span=2^30 -> multiplier==0 path
    int slot = 0, prev = 0;
    #pragma unroll
    for (int i = 0; i < 27; i++) {
        int ci = cum[i];
        if (r >= ci) { slot = i + 1; prev = ci; }
    }
    int pos_in = lo_ws[(size_t)bs * 27 + slot] + (r - prev);
    int src = listB[(size_t)b * NPTS + pos_in];
    src_ws[t] = src;
    out_src[t] = (float)src;
    out_sf[(size_t)b * NPTS + src] = 1.0f;
}

// ---------------- output gather: 16 lanes/row, LDS-staged float4 writes ----
__global__ void k_gather(const float* __restrict__ pos, const float* __restrict__ feat,
                         const int* __restrict__ centers_ws, const int* __restrict__ src_ws,
                         float* __restrict__ out) {
    __shared__ float sbuf[16 * 67];                   // 4288 B
    int t = threadIdx.x;
    int g = t >> 4, q = t & 15;
    long long row0 = (long long)blockIdx.x * 16;      // exact: NB*NS*NN rows
    long long row = row0 + g;
    int b = (int)(row >> 17);
    int u = (int)(row & (NS * NN - 1));
    int s = u >> 5;
    int src = src_ws[row];
    const float4 fv = *(const float4*)(feat + ((size_t)b * NPTS + src) * NCH + 4 * q);
    float* sb = sbuf + g * 67;
    sb[3 + 4 * q + 0] = fv.x;
    sb[3 + 4 * q + 1] = fv.y;
    sb[3 + 4 * q + 2] = fv.z;
    sb[3 + 4 * q + 3] = fv.w;
    if (q < 3) {
        int ctr = centers_ws[b * NS + s];
        sb[q] = pos[((size_t)b * NPTS + src) * 3 + q]
              - pos[((size_t)b * NPTS + ctr) * 3 + q];
    }
    __syncthreads();
    float4* ob = (float4*)(out + (size_t)row0 * 67);  // 4288 B, 16B-aligned
    const float4* sv = (const float4*)sbuf;
    ob[t] = sv[t];
    if (t < 12) ob[256 + t] = sv[256 + t];
}

extern "C" void kernel_launch(void* const* d_in, const int* in_sizes, int n_in,
                              void* d_out, int out_size, void* d_ws, size_t ws_size,
                              hipStream_t stream) {
    (void)in_sizes; (void)n_in; (void)out_size; (void)ws_size;
    const float* pos = (const float*)d_in[0];
    const float* feat = (const float*)d_in[1];
    float* out = (float*)d_out;

    // ---- host-side JAX key-chain (threefry partitionable mode) ----
    RngKeys keys;
    for (int b = 0; b < NB; b++) {
        uint32_t rk0, rk1, kc0, kc1, kn0, kn1;
        tf2x32(0u, 42u, 0u, (uint32_t)b, rk0, rk1);
        tf2x32(rk0, rk1, 0u, 0u, kc0, kc1);
        tf2x32(rk0, rk1, 0u, 1u, kn0, kn1);
        tf2x32(kc0, kc1, 0u, 1u, keys.c0[b], keys.c1[b]);
        tf2x32(kn0, kn1, 0u, 1u, keys.n0[b], keys.n1[b]);
    }

    // ---- workspace layout (~26.2 MB) ----
    int* tab_key    = (int*)d_ws;                    // NB*TSLOTS
    int* tab_cnt    = tab_key + (size_t)NB * TSLOTS; // NB*TSLOTS
    int* bctr       = tab_cnt + (size_t)NB * TSLOTS; // NB  (contiguous w/ tab_cnt)
    int* tab_start  = bctr + NB;                     // NB*TSLOTS
    int* listA      = tab_start + (size_t)NB * TSLOTS; // NB*NPTS
    int* listB      = listA + (size_t)NB * NPTS;     // NB*NPTS
    int* lo_ws      = listB + (size_t)NB * NPTS;     // NB*NS*27
    int* cum_ws     = lo_ws + (size_t)NB * NS * 27;  // NB*NS*27
    int* centers_ws = cum_ws + (size_t)NB * NS * 27; // NB*NS
    int* ctrhk_ws   = centers_ws + (size_t)NB * NS;  // NB*NS
    int* src_ws     = ctrhk_ws + (size_t)NB * NS;    // NB*NS*NN

    // init: keys -> -1; counts + batch counters -> 0; flag outputs -> 0
    hipMemsetAsync(tab_key, 0xFF, (size_t)NB * TSLOTS * 4, stream);
    hipMemsetAsync(tab_cnt, 0, ((size_t)NB * TSLOTS + NB) * 4, stream);
    hipMemsetAsync((char*)d_out + OUT_CF * 4, 0, (size_t)(2 * NB * NPTS) * 4, stream);

    k_insert <<<(NB * NPTS) / 256, 256, 0, stream>>>(pos, tab_key, tab_cnt);
    k_starts <<<(NB * TSLOTS) / 256, 256, 0, stream>>>(tab_cnt, tab_start, bctr);
    k_scatter<<<(NB * NPTS) / 256, 256, 0, stream>>>(pos, tab_key, tab_cnt, tab_start, listA);
    k_rank   <<<(NB * NPTS) / 256, 256, 0, stream>>>(pos, tab_key, tab_cnt, tab_start,
                                                     listA, listB);
    k_centers<<<(NB * NS) / 256, 256, 0, stream>>>(keys, pos, centers_ws, ctrhk_ws,
                                                   out + OUT_CTR, out + OUT_CF);
    k_bins   <<<(NB * NS * 27) / 256, 256, 0, stream>>>(tab_key, tab_cnt, tab_start,
                                                        ctrhk_ws, lo_ws, cum_ws);
    k_cum    <<<(NB * NS) / 256, 256, 0, stream>>>(cum_ws);
    k_select <<<(NB * NS * NN) / 256, 256, 0, stream>>>(keys, listB, lo_ws, cum_ws,
                                                        src_ws, out + OUT_SRC, out + OUT_SF);
    k_gather <<<(NB * NS * NN) / 16, 256, 0, stream>>>(pos, feat, centers_ws, src_ws, out);
}

// Round 5
// 417.008 us; speedup vs baseline: 2.9350x; 1.0455x over previous
//
#include <hip/hip_runtime.h>
#include <stdint.h>

#define NB 8
#define NPTS 100000
#define NS 4096
#define NN 32
#define NCH 64
#define TLG 17
#define TSLOTS (1 << TLG)          // 131072 hash slots per batch
#define TMASK (TSLOTS - 1)

// d_out float layout (element offsets)
#define OUT_MAIN 0ull                          // [8,4096,32,67]
#define OUT_SRC  70254592ull                   // [8,4096,32]
#define OUT_CTR  71303168ull                   // [8,4096]
#define OUT_CF   71335936ull                   // [8,100000]
#define OUT_SF   72135936ull                   // [8,100000]

__host__ __device__ static inline uint32_t rotl32(uint32_t v, int d) {
    return (v << d) | (v >> (32 - d));
}

// JAX threefry2x32 (5 groups of 4 rounds), exact.
__host__ __device__ static inline void tf2x32(uint32_t k0, uint32_t k1,
                                              uint32_t x0, uint32_t x1,
                                              uint32_t& o0, uint32_t& o1) {
    uint32_t ks2 = k0 ^ k1 ^ 0x1BD11BDAu;
    x0 += k0; x1 += k1;
    x0 += x1; x1 = rotl32(x1, 13); x1 ^= x0;
    x0 += x1; x1 = rotl32(x1, 15); x1 ^= x0;
    x0 += x1; x1 = rotl32(x1, 26); x1 ^= x0;
    x0 += x1; x1 = rotl32(x1, 6);  x1 ^= x0;
    x0 += k1; x1 += ks2 + 1u;
    x0 += x1; x1 = rotl32(x1, 17); x1 ^= x0;
    x0 += x1; x1 = rotl32(x1, 29); x1 ^= x0;
    x0 += x1; x1 = rotl32(x1, 16); x1 ^= x0;
    x0 += x1; x1 = rotl32(x1, 24); x1 ^= x0;
    x0 += ks2; x1 += k0 + 2u;
    x0 += x1; x1 = rotl32(x1, 13); x1 ^= x0;
    x0 += x1; x1 = rotl32(x1, 15); x1 ^= x0;
    x0 += x1; x1 = rotl32(x1, 26); x1 ^= x0;
    x0 += x1; x1 = rotl32(x1, 6);  x1 ^= x0;
    x0 += k0; x1 += k1 + 3u;
    x0 += x1; x1 = rotl32(x1, 17); x1 ^= x0;
    x0 += x1; x1 = rotl32(x1, 29); x1 ^= x0;
    x0 += x1; x1 = rotl32(x1, 16); x1 ^= x0;
    x0 += x1; x1 = rotl32(x1, 24); x1 ^= x0;
    x0 += k1; x1 += ks2 + 4u;
    x0 += x1; x1 = rotl32(x1, 13); x1 ^= x0;
    x0 += x1; x1 = rotl32(x1, 15); x1 ^= x0;
    x0 += x1; x1 = rotl32(x1, 26); x1 ^= x0;
    x0 += x1; x1 = rotl32(x1, 6);  x1 ^= x0;
    x0 += ks2; x1 += k0 + 5u;
    o0 = x0; o1 = x1;
}

struct RngKeys {
    uint32_t c0[NB], c1[NB];   // partitionable k2 keys: centers
    uint32_t n0[NB], n1[NB];   // partitionable k2 keys: neighbor draws
};

// partitionable random_bits(key, 32, ...): element u -> o0^o1, counter (0,u)
__device__ static inline uint32_t pbits32(uint32_t k0, uint32_t k1, uint32_t u) {
    uint32_t o0, o1;
    tf2x32(k0, k1, 0u, u, o0, o1);
    return o0 ^ o1;
}

// packed voxel key == reference hash: (vx+512)<<20 | (vy+512)<<10 | (vz+512)
__device__ static inline int voxhash(const float* __restrict__ p) {
    int vx = (int)floorf(p[0] * 4.0f);
    int vy = (int)floorf(p[1] * 4.0f);
    int vz = (int)floorf(p[2] * 4.0f);
    return ((vx + 512) << 20) | ((vy + 512) << 10) | (vz + 512);
}

__device__ static inline int hslot(int hk) {
    return (int)(((uint32_t)hk * 2654435761u) >> (32 - TLG)) & TMASK;
}

// ---------------- P0: init tables + flag outputs (replaces 3 memset nodes) --
__global__ void k_zero(int* __restrict__ tab_key, int* __restrict__ tab_cnt,
                       int* __restrict__ bctr, float4* __restrict__ flags4) {
    int t = blockIdx.x * blockDim.x + threadIdx.x;   // exact: NB*TSLOTS
    tab_key[t] = -1;
    tab_cnt[t] = 0;
    if (t < (2 * NB * NPTS) / 4) flags4[t] = make_float4(0.f, 0.f, 0.f, 0.f);
    if (t < NB) bctr[t] = 0;
}

// ---------------- P1: insert + count (+ remember slot per point) -----------
__global__ void k_insert(const float* __restrict__ pos,
                         int* __restrict__ tab_key, int* __restrict__ tab_cnt,
                         int* __restrict__ slotOf) {
    int t = blockIdx.x * blockDim.x + threadIdx.x;   // exact: NB*NPTS
    int b = t / NPTS;
    int hk = voxhash(pos + (size_t)t * 3);
    int base = b << TLG;
    int slot = hslot(hk);
    while (true) {
        int prev = atomicCAS(&tab_key[base + slot], -1, hk);
        if (prev == -1 || prev == hk) break;
        slot = (slot + 1) & TMASK;
    }
    slotOf[t] = slot;
    atomicAdd(&tab_cnt[base + slot], 1);
}

// ---------------- P2: assign bucket starts (block scan, 1 atomic/block) ----
__global__ void k_starts(int* __restrict__ tab_cnt, int* __restrict__ tab_start,
                         int* __restrict__ bctr) {
    __shared__ int sdata[256];
    __shared__ int sbase;
    int t = blockIdx.x * blockDim.x + threadIdx.x;   // exact: NB*TSLOTS
    int tid = threadIdx.x;
    int b = t >> TLG;                                // uniform per block
    int c = tab_cnt[t];
    sdata[tid] = c;
    __syncthreads();
    for (int off = 1; off < 256; off <<= 1) {        // Hillis-Steele inclusive
        int x = (tid >= off) ? sdata[tid - off] : 0;
        __syncthreads();
        sdata[tid] += x;
        __syncthreads();
    }
    if (tid == 255) sbase = atomicAdd(&bctr[b], sdata[255]);
    __syncthreads();
    if (c > 0) {
        tab_start[t] = sbase + sdata[tid] - c;       // exclusive prefix
        tab_cnt[t] = 0;                              // becomes fill counter
    }
}

// ---------------- P3: scatter arrival order -----------------
__global__ void k_scatter(const int* __restrict__ slotOf, int* __restrict__ tab_cnt,
                          const int* __restrict__ tab_start, int* __restrict__ listA) {
    int t = blockIdx.x * blockDim.x + threadIdx.x;   // exact: NB*NPTS
    int b = t / NPTS, i = t - b * NPTS;
    int slot = (b << TLG) + slotOf[t];
    int a = atomicAdd(&tab_cnt[slot], 1);            // restores cnt as side effect
    listA[(size_t)b * NPTS + tab_start[slot] + a] = i;
}

// ---------------- P4: rank within bucket -> index-sorted lists ------------
__global__ void k_rank(const int* __restrict__ slotOf,
                       const int* __restrict__ tab_cnt, const int* __restrict__ tab_start,
                       const int* __restrict__ listA, int* __restrict__ listB) {
    int t = blockIdx.x * blockDim.x + threadIdx.x;   // exact: NB*NPTS
    int b = t / NPTS, i = t - b * NPTS;
    int slot = (b << TLG) + slotOf[t];
    int s0 = tab_start[slot];
    int c = tab_cnt[slot];
    const int* L = listA + (size_t)b * NPTS + s0;
    int rank = 0;
    for (int k = 0; k < c; k++) rank += (L[k] < i) ? 1 : 0;
    listB[(size_t)b * NPTS + s0 + rank] = i;
}

// ---------------- P5: centers + per-(b,s,bin) bucket lookup (fused) --------
__global__ void k_binsel(RngKeys keys, const float* __restrict__ pos,
                         const int* __restrict__ tab_key, const int* __restrict__ tab_cnt,
                         const int* __restrict__ tab_start,
                         int* __restrict__ centers_ws,
                         int* __restrict__ lo_ws, int* __restrict__ cnt_ws,
                         float* __restrict__ out_ctr, float* __restrict__ out_cf) {
    int t = blockIdx.x * blockDim.x + threadIdx.x;   // exact: NB*NS*27
    int bin = t % 27;
    int bs = t / 27;
    int b = bs >> 12, s = bs & (NS - 1);
    uint32_t lower = pbits32(keys.c0[b], keys.c1[b], (uint32_t)s);
    int c = (int)(lower % 100000u);                  // randint multiplier==0 path
    const float* p = pos + ((size_t)b * NPTS + c) * 3;   // broadcast within group
    // neighbor voxel key by pure integer offset (coords never at the ±512 edge)
    int hk = voxhash(p) + ((bin / 9) - 1) * (1 << 20)
                        + (((bin / 3) % 3) - 1) * (1 << 10)
                        + ((bin % 3) - 1);
    int base = b << TLG;
    int slot = hslot(hk);
    int lo = 0, cnt = 0;
    while (true) {
        int k = tab_key[base + slot];
        if (k == hk) { lo = tab_start[base + slot]; cnt = tab_cnt[base + slot]; break; }
        if (k == -1) break;
        slot = (slot + 1) & TMASK;
    }
    lo_ws[t] = lo;
    cnt_ws[t] = cnt;
    if (bin == 13) {                                 // center voxel thread
        centers_ws[bs] = c;
        out_ctr[bs] = (float)c;
        out_cf[(size_t)b * NPTS + c] = 1.0f;
    }
}

// ---------------- P6: cumsum + neighbor selection (fused) -----------------
__global__ void k_cumsel(RngKeys keys, const int* __restrict__ listB,
                         const int* __restrict__ lo_ws, const int* __restrict__ cnt_ws,
                         int* __restrict__ src_ws,
                         float* __restrict__ out_src, float* __restrict__ out_sf) {
    __shared__ int scnt[216];                        // 8 bs * 27 bins
    __shared__ int slo[216];
    int tid = threadIdx.x;                           // 256 threads, 8 bs/block
    int base216 = blockIdx.x * 216;
    if (tid < 216) {
        scnt[tid] = cnt_ws[base216 + tid];
        slo[tid]  = lo_ws[base216 + tid];
    }
    __syncthreads();
    if (tid < 8) {                                   // serial 27-scan per bs
        int* a = scnt + tid * 27;
        int acc = 0;
        for (int i = 0; i < 27; i++) { acc += a[i]; a[i] = acc; }
    }
    __syncthreads();
    int g = tid >> 5, n = tid & 31;
    int bs = blockIdx.x * 8 + g;
    int b = bs >> 12, s = bs & (NS - 1);
    uint32_t lower = pbits32(keys.n0[b], keys.n1[b], (uint32_t)(s * NN + n));
    const int* cum = scnt + g * 27;
    int total = cum[26];
    int r = (int)(lower & 0x3FFFFFFFu) % total;      // span=2^30 -> multiplier==0 path
    int slot = 0, prev = 0;
    #pragma unroll
    for (int i = 0; i < 27; i++) {
        int ci = cum[i];
        if (r >= ci) { slot = i + 1; prev = ci; }
    }
    int pos_in = slo[g * 27 + slot] + (r - prev);
    int src = listB[(size_t)b * NPTS + pos_in];
    int oi = bs * NN + n;
    src_ws[oi] = src;
    out_src[oi] = (float)src;
    out_sf[(size_t)b * NPTS + src] = 1.0f;
}

// ---------------- P7: output gather: 16 lanes/row, LDS-staged float4 writes
__global__ void k_gather(const float* __restrict__ pos, const float* __restrict__ feat,
                         const int* __restrict__ centers_ws, const int* __restrict__ src_ws,
                         float* __restrict__ out) {
    __shared__ float sbuf[16 * 67];                   // 4288 B
    int t = threadIdx.x;
    int g = t >> 4, q = t & 15;
    long long row0 = (long long)blockIdx.x * 16;      // exact: NB*NS*NN rows
    long long row = row0 + g;
    int b = (int)(row >> 17);
    int u = (int)(row & (NS * NN - 1));
    int s = u >> 5;
    int src = src_ws[row];
    const float4 fv = *(const float4*)(feat + ((size_t)b * NPTS + src) * NCH + 4 * q);
    float* sb = sbuf + g * 67;
    sb[3 + 4 * q + 0] = fv.x;
    sb[3 + 4 * q + 1] = fv.y;
    sb[3 + 4 * q + 2] = fv.z;
    sb[3 + 4 * q + 3] = fv.w;
    if (q < 3) {
        int ctr = centers_ws[b * NS + s];
        sb[q] = pos[((size_t)b * NPTS + src) * 3 + q]
              - pos[((size_t)b * NPTS + ctr) * 3 + q];
    }
    __syncthreads();
    float4* ob = (float4*)(out + (size_t)row0 * 67);  // 4288 B, 16B-aligned
    const float4* sv = (const float4*)sbuf;
    ob[t] = sv[t];
    if (t < 12) ob[256 + t] = sv[256 + t];
}

extern "C" void kernel_launch(void* const* d_in, const int* in_sizes, int n_in,
                              void* d_out, int out_size, void* d_ws, size_t ws_size,
                              hipStream_t stream) {
    (void)in_sizes; (void)n_in; (void)out_size; (void)ws_size;
    const float* pos = (const float*)d_in[0];
    const float* feat = (const float*)d_in[1];
    float* out = (float*)d_out;

    // ---- host-side JAX key-chain (threefry partitionable mode) ----
    RngKeys keys;
    for (int b = 0; b < NB; b++) {
        uint32_t rk0, rk1, kc0, kc1, kn0, kn1;
        tf2x32(0u, 42u, 0u, (uint32_t)b, rk0, rk1);
        tf2x32(rk0, rk1, 0u, 0u, kc0, kc1);
        tf2x32(rk0, rk1, 0u, 1u, kn0, kn1);
        tf2x32(kc0, kc1, 0u, 1u, keys.c0[b], keys.c1[b]);
        tf2x32(kn0, kn1, 0u, 1u, keys.n0[b], keys.n1[b]);
    }

    // ---- workspace layout (~33.6 MB) ----
    int* tab_key    = (int*)d_ws;                      // NB*TSLOTS
    int* tab_cnt    = tab_key + (size_t)NB * TSLOTS;   // NB*TSLOTS
    int* tab_start  = tab_cnt + (size_t)NB * TSLOTS;   // NB*TSLOTS
    int* bctr       = tab_start + (size_t)NB * TSLOTS; // NB
    int* slotOf     = bctr + NB;                       // NB*NPTS
    int* listA      = slotOf + (size_t)NB * NPTS;      // NB*NPTS
    int* listB      = listA + (size_t)NB * NPTS;       // NB*NPTS
    int* lo_ws      = listB + (size_t)NB * NPTS;       // NB*NS*27
    int* cnt_ws     = lo_ws + (size_t)NB * NS * 27;    // NB*NS*27
    int* centers_ws = cnt_ws + (size_t)NB * NS * 27;   // NB*NS
    int* src_ws     = centers_ws + (size_t)NB * NS;    // NB*NS*NN

    k_zero   <<<(NB * TSLOTS) / 256, 256, 0, stream>>>(tab_key, tab_cnt, bctr,
                                                       (float4*)(out + OUT_CF));
    k_insert <<<(NB * NPTS) / 256, 256, 0, stream>>>(pos, tab_key, tab_cnt, slotOf);
    k_starts <<<(NB * TSLOTS) / 256, 256, 0, stream>>>(tab_cnt, tab_start, bctr);
    k_scatter<<<(NB * NPTS) / 256, 256, 0, stream>>>(slotOf, tab_cnt, tab_start, listA);
    k_rank   <<<(NB * NPTS) / 256, 256, 0, stream>>>(slotOf, tab_cnt, tab_start,
                                                     listA, listB);
    k_binsel <<<(NB * NS * 27) / 256, 256, 0, stream>>>(keys, pos, tab_key, tab_cnt,
                                                        tab_start, centers_ws,
                                                        lo_ws, cnt_ws,
                                                        out + OUT_CTR, out + OUT_CF);
    k_cumsel <<<(NB * NS) / 8, 256, 0, stream>>>(keys, listB, lo_ws, cnt_ws,
                                                 src_ws, out + OUT_SRC, out + OUT_SF);
    k_gather <<<(NB * NS * NN) / 16, 256, 0, stream>>>(pos, feat, centers_ws, src_ws, out);
}

// Round 7
// 364.219 us; speedup vs baseline: 3.3604x; 1.1449x over previous
//
#include <hip/hip_runtime.h>
#include <stdint.h>

#define NB 8
#define NPTS 100000
#define NS 4096
#define NN 32
#define NCH 64
#define TLG 17
#define TSLOTS (1 << TLG)          // 131072 hash slots per batch
#define TMASK (TSLOTS - 1)

// d_out float layout (element offsets)
#define OUT_MAIN 0ull                          // [8,4096,32,67]
#define OUT_SRC  70254592ull                   // [8,4096,32]
#define OUT_CTR  71303168ull                   // [8,4096]
#define OUT_CF   71335936ull                   // [8,100000]
#define OUT_SF   72135936ull                   // [8,100000]

typedef float f32x4 __attribute__((ext_vector_type(4)));

__host__ __device__ static inline uint32_t rotl32(uint32_t v, int d) {
    return (v << d) | (v >> (32 - d));
}

// JAX threefry2x32 (5 groups of 4 rounds), exact.
__host__ __device__ static inline void tf2x32(uint32_t k0, uint32_t k1,
                                              uint32_t x0, uint32_t x1,
                                              uint32_t& o0, uint32_t& o1) {
    uint32_t ks2 = k0 ^ k1 ^ 0x1BD11BDAu;
    x0 += k0; x1 += k1;
    x0 += x1; x1 = rotl32(x1, 13); x1 ^= x0;
    x0 += x1; x1 = rotl32(x1, 15); x1 ^= x0;
    x0 += x1; x1 = rotl32(x1, 26); x1 ^= x0;
    x0 += x1; x1 = rotl32(x1, 6);  x1 ^= x0;
    x0 += k1; x1 += ks2 + 1u;
    x0 += x1; x1 = rotl32(x1, 17); x1 ^= x0;
    x0 += x1; x1 = rotl32(x1, 29); x1 ^= x0;
    x0 += x1; x1 = rotl32(x1, 16); x1 ^= x0;
    x0 += x1; x1 = rotl32(x1, 24); x1 ^= x0;
    x0 += ks2; x1 += k0 + 2u;
    x0 += x1; x1 = rotl32(x1, 13); x1 ^= x0;
    x0 += x1; x1 = rotl32(x1, 15); x1 ^= x0;
    x0 += x1; x1 = rotl32(x1, 26); x1 ^= x0;
    x0 += x1; x1 = rotl32(x1, 6);  x1 ^= x0;
    x0 += k0; x1 += k1 + 3u;
    x0 += x1; x1 = rotl32(x1, 17); x1 ^= x0;
    x0 += x1; x1 = rotl32(x1, 29); x1 ^= x0;
    x0 += x1; x1 = rotl32(x1, 16); x1 ^= x0;
    x0 += x1; x1 = rotl32(x1, 24); x1 ^= x0;
    x0 += k1; x1 += ks2 + 4u;
    x0 += x1; x1 = rotl32(x1, 13); x1 ^= x0;
    x0 += x1; x1 = rotl32(x1, 15); x1 ^= x0;
    x0 += x1; x1 = rotl32(x1, 26); x1 ^= x0;
    x0 += x1; x1 = rotl32(x1, 6);  x1 ^= x0;
    x0 += ks2; x1 += k0 + 5u;
    o0 = x0; o1 = x1;
}

struct RngKeys {
    uint32_t c0[NB], c1[NB];   // partitionable k2 keys: centers
    uint32_t n0[NB], n1[NB];   // partitionable k2 keys: neighbor draws
};

// partitionable random_bits(key, 32, ...): element u -> o0^o1, counter (0,u)
__device__ static inline uint32_t pbits32(uint32_t k0, uint32_t k1, uint32_t u) {
    uint32_t o0, o1;
    tf2x32(k0, k1, 0u, u, o0, o1);
    return o0 ^ o1;
}

// packed voxel key == reference hash: (vx+512)<<20 | (vy+512)<<10 | (vz+512)
__device__ static inline int voxhash(const float* __restrict__ p) {
    int vx = (int)floorf(p[0] * 4.0f);
    int vy = (int)floorf(p[1] * 4.0f);
    int vz = (int)floorf(p[2] * 4.0f);
    return ((vx + 512) << 20) | ((vy + 512) << 10) | (vz + 512);
}

__device__ static inline int hslot(int hk) {
    return (int)(((uint32_t)hk * 2654435761u) >> (32 - TLG)) & TMASK;
}

// ---------------- P0: init tables + flag outputs -----------------
__global__ void k_zero(int* __restrict__ tab_key, int* __restrict__ tab_cnt,
                       int* __restrict__ bctr, float4* __restrict__ flags4) {
    int t = blockIdx.x * blockDim.x + threadIdx.x;   // exact: NB*TSLOTS
    tab_key[t] = -1;
    tab_cnt[t] = 0;
    if (t < (2 * NB * NPTS) / 4) flags4[t] = make_float4(0.f, 0.f, 0.f, 0.f);
    if (t < NB) bctr[t] = 0;
}

// ---------------- P1: insert + count (+ remember slot per point) -----------
__global__ void k_insert(const float* __restrict__ pos,
                         int* __restrict__ tab_key, int* __restrict__ tab_cnt,
                         int* __restrict__ slotOf) {
    int t = blockIdx.x * blockDim.x + threadIdx.x;   // exact: NB*NPTS
    int b = t / NPTS;
    int hk = voxhash(pos + (size_t)t * 3);
    int base = b << TLG;
    int slot = hslot(hk);
    while (true) {
        int prev = atomicCAS(&tab_key[base + slot], -1, hk);
        if (prev == -1 || prev == hk) break;
        slot = (slot + 1) & TMASK;
    }
    slotOf[t] = slot;
    atomicAdd(&tab_cnt[base + slot], 1);
}

// ---------------- P2: assign bucket starts (block scan, 1 atomic/block) ----
__global__ void k_starts(int* __restrict__ tab_cnt, int* __restrict__ tab_start,
                         int* __restrict__ bctr) {
    __shared__ int sdata[256];
    __shared__ int sbase;
    int t = blockIdx.x * blockDim.x + threadIdx.x;   // exact: NB*TSLOTS
    int tid = threadIdx.x;
    int b = t >> TLG;                                // uniform per block
    int c = tab_cnt[t];
    sdata[tid] = c;
    __syncthreads();
    for (int off = 1; off < 256; off <<= 1) {        // Hillis-Steele inclusive
        int x = (tid >= off) ? sdata[tid - off] : 0;
        __syncthreads();
        sdata[tid] += x;
        __syncthreads();
    }
    if (tid == 255) sbase = atomicAdd(&bctr[b], sdata[255]);
    __syncthreads();
    if (c > 0) {
        tab_start[t] = sbase + sdata[tid] - c;       // exclusive prefix
        tab_cnt[t] = 0;                              // becomes fill counter
    }
}

// ---------------- P3: scatter arrival order -----------------
__global__ void k_scatter(const int* __restrict__ slotOf, int* __restrict__ tab_cnt,
                          const int* __restrict__ tab_start, int* __restrict__ listA) {
    int t = blockIdx.x * blockDim.x + threadIdx.x;   // exact: NB*NPTS
    int b = t / NPTS, i = t - b * NPTS;
    int slot = (b << TLG) + slotOf[t];
    int a = atomicAdd(&tab_cnt[slot], 1);            // restores cnt as side effect
    listA[(size_t)b * NPTS + tab_start[slot] + a] = i;
}

// ---------------- P4: rank within bucket -> index-sorted lists ------------
__global__ void k_rank(const int* __restrict__ slotOf,
                       const int* __restrict__ tab_cnt, const int* __restrict__ tab_start,
                       const int* __restrict__ listA, int* __restrict__ listB) {
    int t = blockIdx.x * blockDim.x + threadIdx.x;   // exact: NB*NPTS
    int b = t / NPTS, i = t - b * NPTS;
    int slot = (b << TLG) + slotOf[t];
    int s0 = tab_start[slot];
    int c = tab_cnt[slot];
    const int* L = listA + (size_t)b * NPTS + s0;
    int rank = 0;
    for (int k = 0; k < c; k++) rank += (L[k] < i) ? 1 : 0;
    listB[(size_t)b * NPTS + s0 + rank] = i;
}

// ------- P5: centers + 27-bin lookup + cumsum + selection (fully fused) ----
// 32 threads per sample: lanes 0..26 probe bins into LDS, all 32 select.
__global__ void k_sel(RngKeys keys, const float* __restrict__ pos,
                      const int* __restrict__ tab_key, const int* __restrict__ tab_cnt,
                      const int* __restrict__ tab_start, const int* __restrict__ listB,
                      int* __restrict__ centers_ws, int* __restrict__ src_ws,
                      float* __restrict__ out_ctr, float* __restrict__ out_cf,
                      float* __restrict__ out_src, float* __restrict__ out_sf) {
    __shared__ int scnt[8][27];
    __shared__ int slo[8][27];
    int tid = threadIdx.x;                           // 256 threads = 8 samples
    int g = tid >> 5, n = tid & 31;
    int bs = blockIdx.x * 8 + g;                     // exact: NB*NS/8 blocks
    int b = bs >> 12, s = bs & (NS - 1);
    uint32_t lower_c = pbits32(keys.c0[b], keys.c1[b], (uint32_t)s);
    int c = (int)(lower_c % 100000u);                // randint multiplier==0 path
    const float* p = pos + ((size_t)b * NPTS + c) * 3;
    int chk = voxhash(p);                            // same 12B for 32 lanes -> L1
    if (n < 27) {
        // neighbor voxel key by integer offset (coords never at the ±512 edge)
        int hk = chk + ((n / 9) - 1) * (1 << 20)
                     + (((n / 3) % 3) - 1) * (1 << 10)
                     + ((n % 3) - 1);
        int base = b << TLG;
        int slot = hslot(hk);
        int lo = 0, cnt = 0;
        while (true) {
            int k = tab_key[base + slot];
            if (k == hk) { lo = tab_start[base + slot]; cnt = tab_cnt[base + slot]; break; }
            if (k == -1) break;
            slot = (slot + 1) & TMASK;
        }
        scnt[g][n] = cnt;
        slo[g][n] = lo;
    }
    if (n == 0) {
        centers_ws[bs] = c;
        out_ctr[bs] = (float)c;
        out_cf[(size_t)b * NPTS + c] = 1.0f;
    }
    __syncthreads();
    uint32_t lower = pbits32(keys.n0[b], keys.n1[b], (uint32_t)(s * NN + n));
    int total = 0;
    #pragma unroll
    for (int i = 0; i < 27; i++) total += scnt[g][i];
    int r = (int)(lower & 0x3FFFFFFFu) % total;      // span=2^30 -> multiplier==0 path
    int slot = 0, prev = 0, acc = 0;
    #pragma unroll
    for (int i = 0; i < 27; i++) {
        acc += scnt[g][i];
        if (r >= acc) { slot = i + 1; prev = acc; }
    }
    int pos_in = slo[g][slot] + (r - prev);
    int src = listB[(size_t)b * NPTS + pos_in];
    int oi = bs * NN + n;
    src_ws[oi] = src;
    out_src[oi] = (float)src;
    out_sf[(size_t)b * NPTS + src] = 1.0f;
}

// ---- P6: output gather: 16 lanes/row, 32 rows/block, nontemporal stores ----
__global__ void k_gather(const float* __restrict__ pos, const float* __restrict__ feat,
                         const int* __restrict__ centers_ws, const int* __restrict__ src_ws,
                         float* __restrict__ out) {
    __shared__ float sbuf[32 * 67];                   // 8576 B
    int t = threadIdx.x;                              // 512 threads
    int g = t >> 4, q = t & 15;
    long long row0 = (long long)blockIdx.x * 32;      // exact: NB*NS*NN rows
    long long row = row0 + g;
    int b = (int)(row >> 17);
    int u = (int)(row & (NS * NN - 1));
    int s = u >> 5;
    int src = src_ws[row];
    const float4 fv = *(const float4*)(feat + ((size_t)b * NPTS + src) * NCH + 4 * q);
    float* sb = sbuf + g * 67;
    sb[3 + 4 * q + 0] = fv.x;
    sb[3 + 4 * q + 1] = fv.y;
    sb[3 + 4 * q + 2] = fv.z;
    sb[3 + 4 * q + 3] = fv.w;
    if (q < 3) {
        int ctr = centers_ws[b * NS + s];
        sb[q] = pos[((size_t)b * NPTS + src) * 3 + q]
              - pos[((size_t)b * NPTS + ctr) * 3 + q];
    }
    __syncthreads();
    // 32*67 = 2144 floats = 536 float4, contiguous & 16B-aligned per block.
    // Output is write-once, never re-read on device -> nontemporal (keep L3 for feat).
    f32x4* ob = (f32x4*)(out + (size_t)row0 * 67);
    const f32x4* sv = (const f32x4*)sbuf;
    __builtin_nontemporal_store(sv[t], &ob[t]);
    if (t < 24) __builtin_nontemporal_store(sv[512 + t], &ob[512 + t]);
}

extern "C" void kernel_launch(void* const* d_in, const int* in_sizes, int n_in,
                              void* d_out, int out_size, void* d_ws, size_t ws_size,
                              hipStream_t stream) {
    (void)in_sizes; (void)n_in; (void)out_size; (void)ws_size;
    const float* pos = (const float*)d_in[0];
    const float* feat = (const float*)d_in[1];
    float* out = (float*)d_out;

    // ---- host-side JAX key-chain (threefry partitionable mode) ----
    RngKeys keys;
    for (int b = 0; b < NB; b++) {
        uint32_t rk0, rk1, kc0, kc1, kn0, kn1;
        tf2x32(0u, 42u, 0u, (uint32_t)b, rk0, rk1);
        tf2x32(rk0, rk1, 0u, 0u, kc0, kc1);
        tf2x32(rk0, rk1, 0u, 1u, kn0, kn1);
        tf2x32(kc0, kc1, 0u, 1u, keys.c0[b], keys.c1[b]);
        tf2x32(kn0, kn1, 0u, 1u, keys.n0[b], keys.n1[b]);
    }

    // ---- workspace layout (~26.5 MB) ----
    int* tab_key    = (int*)d_ws;                      // NB*TSLOTS
    int* tab_cnt    = tab_key + (size_t)NB * TSLOTS;   // NB*TSLOTS
    int* tab_start  = tab_cnt + (size_t)NB * TSLOTS;   // NB*TSLOTS
    int* bctr       = tab_start + (size_t)NB * TSLOTS; // NB
    int* slotOf     = bctr + NB;                       // NB*NPTS
    int* listA      = slotOf + (size_t)NB * NPTS;      // NB*NPTS
    int* listB      = listA + (size_t)NB * NPTS;       // NB*NPTS
    int* centers_ws = listB + (size_t)NB * NPTS;       // NB*NS
    int* src_ws     = centers_ws + (size_t)NB * NS;    // NB*NS*NN

    k_zero   <<<(NB * TSLOTS) / 256, 256, 0, stream>>>(tab_key, tab_cnt, bctr,
                                                       (float4*)(out + OUT_CF));
    k_insert <<<(NB * NPTS) / 256, 256, 0, stream>>>(pos, tab_key, tab_cnt, slotOf);
    k_starts <<<(NB * TSLOTS) / 256, 256, 0, stream>>>(tab_cnt, tab_start, bctr);
    k_scatter<<<(NB * NPTS) / 256, 256, 0, stream>>>(slotOf, tab_cnt, tab_start, listA);
    k_rank   <<<(NB * NPTS) / 256, 256, 0, stream>>>(slotOf, tab_cnt, tab_start,
                                                     listA, listB);
    k_sel    <<<(NB * NS) / 8, 256, 0, stream>>>(keys, pos, tab_key, tab_cnt, tab_start,
                                                 listB, centers_ws, src_ws,
                                                 out + OUT_CTR, out + OUT_CF,
                                                 out + OUT_SRC, out + OUT_SF);
    k_gather <<<(NB * NS * NN) / 32, 512, 0, stream>>>(pos, feat, centers_ws, src_ws, out);
}

// Round 8
// 359.102 us; speedup vs baseline: 3.4083x; 1.0143x over previous
//
#include <hip/hip_runtime.h>
#include <stdint.h>

#define NB 8
#define NPTS 100000
#define NS 4096
#define NN 32
#define NCH 64
#define TLG 17
#define TSLOTS (1 << TLG)          // 131072 hash slots per batch
#define TMASK (TSLOTS - 1)

// d_out float layout (element offsets)
#define OUT_MAIN 0ull                          // [8,4096,32,67]
#define OUT_SRC  70254592ull                   // [8,4096,32]
#define OUT_CTR  71303168ull                   // [8,4096]
#define OUT_CF   71335936ull                   // [8,100000]
#define OUT_SF   72135936ull                   // [8,100000]

typedef float f32x4 __attribute__((ext_vector_type(4)));

__host__ __device__ static inline uint32_t rotl32(uint32_t v, int d) {
    return (v << d) | (v >> (32 - d));
}

// JAX threefry2x32 (5 groups of 4 rounds), exact.
__host__ __device__ static inline void tf2x32(uint32_t k0, uint32_t k1,
                                              uint32_t x0, uint32_t x1,
                                              uint32_t& o0, uint32_t& o1) {
    uint32_t ks2 = k0 ^ k1 ^ 0x1BD11BDAu;
    x0 += k0; x1 += k1;
    x0 += x1; x1 = rotl32(x1, 13); x1 ^= x0;
    x0 += x1; x1 = rotl32(x1, 15); x1 ^= x0;
    x0 += x1; x1 = rotl32(x1, 26); x1 ^= x0;
    x0 += x1; x1 = rotl32(x1, 6);  x1 ^= x0;
    x0 += k1; x1 += ks2 + 1u;
    x0 += x1; x1 = rotl32(x1, 17); x1 ^= x0;
    x0 += x1; x1 = rotl32(x1, 29); x1 ^= x0;
    x0 += x1; x1 = rotl32(x1, 16); x1 ^= x0;
    x0 += x1; x1 = rotl32(x1, 24); x1 ^= x0;
    x0 += ks2; x1 += k0 + 2u;
    x0 += x1; x1 = rotl32(x1, 13); x1 ^= x0;
    x0 += x1; x1 = rotl32(x1, 15); x1 ^= x0;
    x0 += x1; x1 = rotl32(x1, 26); x1 ^= x0;
    x0 += x1; x1 = rotl32(x1, 6);  x1 ^= x0;
    x0 += k0; x1 += k1 + 3u;
    x0 += x1; x1 = rotl32(x1, 17); x1 ^= x0;
    x0 += x1; x1 = rotl32(x1, 29); x1 ^= x0;
    x0 += x1; x1 = rotl32(x1, 16); x1 ^= x0;
    x0 += x1; x1 = rotl32(x1, 24); x1 ^= x0;
    x0 += k1; x1 += ks2 + 4u;
    x0 += x1; x1 = rotl32(x1, 13); x1 ^= x0;
    x0 += x1; x1 = rotl32(x1, 15); x1 ^= x0;
    x0 += x1; x1 = rotl32(x1, 26); x1 ^= x0;
    x0 += x1; x1 = rotl32(x1, 6);  x1 ^= x0;
    x0 += ks2; x1 += k0 + 5u;
    o0 = x0; o1 = x1;
}

struct RngKeys {
    uint32_t c0[NB], c1[NB];   // partitionable k2 keys: centers
    uint32_t n0[NB], n1[NB];   // partitionable k2 keys: neighbor draws
};

// partitionable random_bits(key, 32, ...): element u -> o0^o1, counter (0,u)
__device__ static inline uint32_t pbits32(uint32_t k0, uint32_t k1, uint32_t u) {
    uint32_t o0, o1;
    tf2x32(k0, k1, 0u, u, o0, o1);
    return o0 ^ o1;
}

// packed voxel key == reference hash: (vx+512)<<20 | (vy+512)<<10 | (vz+512)
__device__ static inline int voxhash(const float* __restrict__ p) {
    int vx = (int)floorf(p[0] * 4.0f);
    int vy = (int)floorf(p[1] * 4.0f);
    int vz = (int)floorf(p[2] * 4.0f);
    return ((vx + 512) << 20) | ((vy + 512) << 10) | (vz + 512);
}

__device__ static inline int hslot(int hk) {
    return (int)(((uint32_t)hk * 2654435761u) >> (32 - TLG)) & TMASK;
}

// ---------------- P0: init tables + flag outputs -----------------
__global__ void k_zero(int* __restrict__ tab_key, int* __restrict__ tab_cnt,
                       int* __restrict__ bctr, float4* __restrict__ flags4) {
    int t = blockIdx.x * blockDim.x + threadIdx.x;   // exact: NB*TSLOTS
    tab_key[t] = -1;
    tab_cnt[t] = 0;
    if (t < (2 * NB * NPTS) / 4) flags4[t] = make_float4(0.f, 0.f, 0.f, 0.f);
    if (t < NB) bctr[t] = 0;
}

// ---------------- P1: insert + count (+ remember slot per point) -----------
__global__ void k_insert(const float* __restrict__ pos,
                         int* __restrict__ tab_key, int* __restrict__ tab_cnt,
                         int* __restrict__ slotOf) {
    int t = blockIdx.x * blockDim.x + threadIdx.x;   // exact: NB*NPTS
    int b = t / NPTS;
    int hk = voxhash(pos + (size_t)t * 3);
    int base = b << TLG;
    int slot = hslot(hk);
    while (true) {
        int prev = atomicCAS(&tab_key[base + slot], -1, hk);
        if (prev == -1 || prev == hk) break;
        slot = (slot + 1) & TMASK;
    }
    slotOf[t] = slot;
    atomicAdd(&tab_cnt[base + slot], 1);
}

// ---------------- P2: assign bucket starts (block scan, 1 atomic/block) ----
__global__ void k_starts(int* __restrict__ tab_cnt, int* __restrict__ tab_start,
                         int* __restrict__ bctr) {
    __shared__ int sdata[256];
    __shared__ int sbase;
    int t = blockIdx.x * blockDim.x + threadIdx.x;   // exact: NB*TSLOTS
    int tid = threadIdx.x;
    int b = t >> TLG;                                // uniform per block
    int c = tab_cnt[t];
    sdata[tid] = c;
    __syncthreads();
    for (int off = 1; off < 256; off <<= 1) {        // Hillis-Steele inclusive
        int x = (tid >= off) ? sdata[tid - off] : 0;
        __syncthreads();
        sdata[tid] += x;
        __syncthreads();
    }
    if (tid == 255) sbase = atomicAdd(&bctr[b], sdata[255]);
    __syncthreads();
    if (c > 0) {
        tab_start[t] = sbase + sdata[tid] - c;       // exclusive prefix
        tab_cnt[t] = 0;                              // becomes fill counter
    }
}

// ---------------- P3: scatter arrival order -----------------
__global__ void k_scatter(const int* __restrict__ slotOf, int* __restrict__ tab_cnt,
                          const int* __restrict__ tab_start, int* __restrict__ listA) {
    int t = blockIdx.x * blockDim.x + threadIdx.x;   // exact: NB*NPTS
    int b = t / NPTS, i = t - b * NPTS;
    int slot = (b << TLG) + slotOf[t];
    int a = atomicAdd(&tab_cnt[slot], 1);            // restores cnt as side effect
    listA[(size_t)b * NPTS + tab_start[slot] + a] = i;
}

// ---------------- P4: rank within bucket -> index-sorted lists ------------
__global__ void k_rank(const int* __restrict__ slotOf,
                       const int* __restrict__ tab_cnt, const int* __restrict__ tab_start,
                       const int* __restrict__ listA, int* __restrict__ listB) {
    int t = blockIdx.x * blockDim.x + threadIdx.x;   // exact: NB*NPTS
    int b = t / NPTS, i = t - b * NPTS;
    int slot = (b << TLG) + slotOf[t];
    int s0 = tab_start[slot];
    int c = tab_cnt[slot];
    const int* L = listA + (size_t)b * NPTS + s0;
    int rank = 0;
    for (int k = 0; k < c; k++) rank += (L[k] < i) ? 1 : 0;
    listB[(size_t)b * NPTS + s0 + rank] = i;
}

// ------- P5: centers + 27-bin lookup + cumsum + selection (fully fused) ----
// 32 threads per sample: lanes 0..26 probe bins into LDS, all 32 select.
__global__ void k_sel(RngKeys keys, const float* __restrict__ pos,
                      const int* __restrict__ tab_key, const int* __restrict__ tab_cnt,
                      const int* __restrict__ tab_start, const int* __restrict__ listB,
                      int* __restrict__ centers_ws, int* __restrict__ src_ws,
                      float* __restrict__ out_ctr, float* __restrict__ out_cf,
                      float* __restrict__ out_src, float* __restrict__ out_sf) {
    __shared__ int scnt[8][27];
    __shared__ int slo[8][27];
    int tid = threadIdx.x;                           // 256 threads = 8 samples
    int g = tid >> 5, n = tid & 31;
    int bs = blockIdx.x * 8 + g;                     // exact: NB*NS/8 blocks
    int b = bs >> 12, s = bs & (NS - 1);
    uint32_t lower_c = pbits32(keys.c0[b], keys.c1[b], (uint32_t)s);
    int c = (int)(lower_c % 100000u);                // randint multiplier==0 path
    const float* p = pos + ((size_t)b * NPTS + c) * 3;
    int chk = voxhash(p);                            // same 12B for 32 lanes -> L1
    if (n < 27) {
        // neighbor voxel key by integer offset (coords never at the ±512 edge)
        int hk = chk + ((n / 9) - 1) * (1 << 20)
                     + (((n / 3) % 3) - 1) * (1 << 10)
                     + ((n % 3) - 1);
        int base = b << TLG;
        int slot = hslot(hk);
        int lo = 0, cnt = 0;
        while (true) {
            int k = tab_key[base + slot];
            if (k == hk) { lo = tab_start[base + slot]; cnt = tab_cnt[base + slot]; break; }
            if (k == -1) break;
            slot = (slot + 1) & TMASK;
        }
        scnt[g][n] = cnt;
        slo[g][n] = lo;
    }
    if (n == 0) {
        centers_ws[bs] = c;
        out_ctr[bs] = (float)c;
        out_cf[(size_t)b * NPTS + c] = 1.0f;
    }
    __syncthreads();
    uint32_t lower = pbits32(keys.n0[b], keys.n1[b], (uint32_t)(s * NN + n));
    int total = 0;
    #pragma unroll
    for (int i = 0; i < 27; i++) total += scnt[g][i];
    int r = (int)(lower & 0x3FFFFFFFu) % total;      // span=2^30 -> multiplier==0 path
    int slot = 0, prev = 0, acc = 0;
    #pragma unroll
    for (int i = 0; i < 27; i++) {
        acc += scnt[g][i];
        if (r >= acc) { slot = i + 1; prev = acc; }
    }
    int pos_in = slo[g][slot] + (r - prev);
    int src = listB[(size_t)b * NPTS + pos_in];
    int oi = bs * NN + n;
    src_ws[oi] = src;
    out_src[oi] = (float)src;
    out_sf[(size_t)b * NPTS + src] = 1.0f;
}

// ---- P6: output gather: 64 rows/block, 2 independent feat loads/thread ----
__global__ void k_gather(const float* __restrict__ pos, const float* __restrict__ feat,
                         const int* __restrict__ centers_ws, const int* __restrict__ src_ws,
                         float* __restrict__ out) {
    __shared__ float sbuf[64 * 67];                   // 17152 B
    int t = threadIdx.x;                              // 512 threads
    long long row0 = (long long)blockIdx.x * 64;      // exact: NB*NS*NN rows
    // two feat-quarter slots per thread -> 2 loads in flight (MLP)
    int g0 = t >> 4,          q0 = t & 15;
    int g1 = (t + 512) >> 4,  q1 = t & 15;            // (t+512)&15 == t&15
    long long rowA = row0 + g0, rowB = row0 + g1;
    int bA = (int)(rowA >> 17), bB = (int)(rowB >> 17);
    int srcA = src_ws[rowA];
    int srcB = src_ws[rowB];
    const float4 fvA = *(const float4*)(feat + ((size_t)bA * NPTS + srcA) * NCH + 4 * q0);
    const float4 fvB = *(const float4*)(feat + ((size_t)bB * NPTS + srcB) * NCH + 4 * q1);
    float* sbA = sbuf + g0 * 67;
    sbA[3 + 4 * q0 + 0] = fvA.x;
    sbA[3 + 4 * q0 + 1] = fvA.y;
    sbA[3 + 4 * q0 + 2] = fvA.z;
    sbA[3 + 4 * q0 + 3] = fvA.w;
    float* sbB = sbuf + g1 * 67;
    sbB[3 + 4 * q1 + 0] = fvB.x;
    sbB[3 + 4 * q1 + 1] = fvB.y;
    sbB[3 + 4 * q1 + 2] = fvB.z;
    sbB[3 + 4 * q1 + 3] = fvB.w;
    if (t < 192) {                                    // rel: 3 floats x 64 rows
        int g = t / 3, q = t - g * 3;
        long long row = row0 + g;
        int b = (int)(row >> 17);
        int u = (int)(row & (NS * NN - 1));
        int s = u >> 5;
        int src = src_ws[row];
        int ctr = centers_ws[b * NS + s];
        sbuf[g * 67 + q] = pos[((size_t)b * NPTS + src) * 3 + q]
                         - pos[((size_t)b * NPTS + ctr) * 3 + q];
    }
    __syncthreads();
    // 64*67 = 4288 floats = 1072 float4, contiguous & 16B-aligned per block.
    // Output is write-once, never re-read on device -> nontemporal (keep L3 for feat).
    f32x4* ob = (f32x4*)(out + (size_t)row0 * 67);
    const f32x4* sv = (const f32x4*)sbuf;
    __builtin_nontemporal_store(sv[t], &ob[t]);
    __builtin_nontemporal_store(sv[t + 512], &ob[t + 512]);
    if (t < 48) __builtin_nontemporal_store(sv[t + 1024], &ob[t + 1024]);
}

extern "C" void kernel_launch(void* const* d_in, const int* in_sizes, int n_in,
                              void* d_out, int out_size, void* d_ws, size_t ws_size,
                              hipStream_t stream) {
    (void)in_sizes; (void)n_in; (void)out_size; (void)ws_size;
    const float* pos = (const float*)d_in[0];
    const float* feat = (const float*)d_in[1];
    float* out = (float*)d_out;

    // ---- host-side JAX key-chain (threefry partitionable mode) ----
    RngKeys keys;
    for (int b = 0; b < NB; b++) {
        uint32_t rk0, rk1, kc0, kc1, kn0, kn1;
        tf2x32(0u, 42u, 0u, (uint32_t)b, rk0, rk1);
        tf2x32(rk0, rk1, 0u, 0u, kc0, kc1);
        tf2x32(rk0, rk1, 0u, 1u, kn0, kn1);
        tf2x32(kc0, kc1, 0u, 1u, keys.c0[b], keys.c1[b]);
        tf2x32(kn0, kn1, 0u, 1u, keys.n0[b], keys.n1[b]);
    }

    // ---- workspace layout (~26.5 MB) ----
    int* tab_key    = (int*)d_ws;                      // NB*TSLOTS
    int* tab_cnt    = tab_key + (size_t)NB * TSLOTS;   // NB*TSLOTS
    int* tab_start  = tab_cnt + (size_t)NB * TSLOTS;   // NB*TSLOTS
    int* bctr       = tab_start + (size_t)NB * TSLOTS; // NB
    int* slotOf     = bctr + NB;                       // NB*NPTS
    int* listA      = slotOf + (size_t)NB * NPTS;      // NB*NPTS
    int* listB      = listA + (size_t)NB * NPTS;       // NB*NPTS
    int* centers_ws = listB + (size_t)NB * NPTS;       // NB*NS
    int* src_ws     = centers_ws + (size_t)NB * NS;    // NB*NS*NN

    k_zero   <<<(NB * TSLOTS) / 256, 256, 0, stream>>>(tab_key, tab_cnt, bctr,
                                                       (float4*)(out + OUT_CF));
    k_insert <<<(NB * NPTS) / 256, 256, 0, stream>>>(pos, tab_key, tab_cnt, slotOf);
    k_starts <<<(NB * TSLOTS) / 256, 256, 0, stream>>>(tab_cnt, tab_start, bctr);
    k_scatter<<<(NB * NPTS) / 256, 256, 0, stream>>>(slotOf, tab_cnt, tab_start, listA);
    k_rank   <<<(NB * NPTS) / 256, 256, 0, stream>>>(slotOf, tab_cnt, tab_start,
                                                     listA, listB);
    k_sel    <<<(NB * NS) / 8, 256, 0, stream>>>(keys, pos, tab_key, tab_cnt, tab_start,
                                                 listB, centers_ws, src_ws,
                                                 out + OUT_CTR, out + OUT_CF,
                                                 out + OUT_SRC, out + OUT_SF);
    k_gather <<<(NB * NS * NN) / 64, 512, 0, stream>>>(pos, feat, centers_ws, src_ws, out);
}